// Round 18
// baseline (146.249 us; speedup 1.0000x reference)
//
#include <hip/hip_runtime.h>

// Problem dims (fixed by reference)
#define T_TOTAL (32 * 4096)   // B*S = 131072 tokens
#define FDIM 256
#define NG 2                  // groups
#define NN 128                // entries per group
#define DDIM 128              // group dim
#define EDIM 256              // embed dim

#define TAU 0.004f            // bf16x3-vs-f32 safety margin for argmax gap
#define CAP 16384             // max flagged (t,g) entries (expected ~1k)

typedef __attribute__((ext_vector_type(4))) float f32x4;
typedef __attribute__((ext_vector_type(8))) short short8;
typedef __attribute__((ext_vector_type(4))) short s16x4;

// ---------------------------------------------------------------------------
// Kernel P (prep): CO = codebooks @ W_out slices ; BT = split-bf16 W^T ;
// zero flag counter. One block per (g,n) = 256 blocks x 256 threads.
// ---------------------------------------------------------------------------
__global__ __launch_bounds__(256) void prep_kernel(
    const float* __restrict__ codebooks,  // [2][128][128]
    const float* __restrict__ W_out,      // [256][256]
    const float* __restrict__ Wl,         // [2][128 k][128 n]
    float* __restrict__ CO,               // [2][128][256]
    short* __restrict__ BT,               // [2 lev][2 g][128 n][128 k]
    int* __restrict__ flag_count)
{
    const int gn  = blockIdx.x;           // g*128 + n
    const int g   = gn >> 7;
    const int tid = threadIdx.x;
    __shared__ float cb[DDIM];
    if (tid < DDIM) cb[tid] = codebooks[gn * DDIM + tid];
    if (tid >= 128) {
        const int k = tid - 128;
        const int n = gn & 127;
        const float x = Wl[((size_t)g * DDIM + k) * NN + n];
        const unsigned u = __float_as_uint(x);
        const float hi = __uint_as_float(u & 0xffff0000u);
        const unsigned u2 = __float_as_uint(x - hi);   // exact residual
        BT[(size_t)g * 16384 + n * 128 + k] = (short)(u >> 16);
        BT[32768 + (size_t)g * 16384 + n * 128 + k] = (short)(u2 >> 16);
    }
    if (gn == 0 && tid == 0) *flag_count = 0;
    __syncthreads();
    float acc = 0.f;
    const float* wcol = W_out + (g * DDIM) * EDIM + tid;
#pragma unroll 4
    for (int d = 0; d < DDIM; ++d) acc += cb[d] * wcol[d * EDIM];
    CO[gn * EDIM + tid] = acc;
}

// ---------------------------------------------------------------------------
// Kernel M (main v19, fused): block = 1024 thr = 16 waves = 2 g x 8 n-tiles;
// 256 tokens over 4 stages of 64. TRUE dense staging: instruction c loads a
// contiguous 16KB slab with lane-stride 16B (elem idx = c*1024+tid -> token
// c*16+w, slot l): 16 fully-used lines/instr (r8: 64 lines/instr; r17's
// "flat" copy was still 64B lane-stride). PLAIN C loads (r17's asm-loads at
// 1024 thr -> aperture violation; compiler-managed waits are safe; kernel is
// delivery-BW-bound so exposed latency ~10%). F split once -> hi/lo bf16
// planes in 64KB LDS (chunk ^ tok&7 swizzle, conflict-free at inherent
// minimum); G raw f32x4 in 64KB LDS (slot ^ tok&7). W in regs (r11 layout).
// Per stage: load+split -> barrier-A -> ds_write + combine(st-1) [race-safe
// slot] -> barrier-B -> out-write(st-1) + compute(st).
// Numerics byte-identical to r5-r16 (same split, TAU, argmax, fixup).
// ---------------------------------------------------------------------------
__global__ __launch_bounds__(1024) void pq_v19_kernel(
    const float* __restrict__ features,   // [T][256]
    const float* __restrict__ gumbel,     // [T][2][128]
    const short* __restrict__ BT,         // [2 lev][2 g][128 n][128 k]
    const float* __restrict__ bl,         // [2][128]
    const float* __restrict__ CO,         // [2][128][256]
    const float* __restrict__ b_out,      // [256]
    float* __restrict__ out,              // [T][256]
    float* __restrict__ idx_f,            // [T][2] float-encoded indices
    int* __restrict__ flag_count,
    int* __restrict__ flag_list)
{
    __shared__ s16x4 Flds4[8192];                 // 64 KB: hi [0..4095], lo [4096..]
    __shared__ __align__(16) float Glds[16384];   // 64 KB
    __shared__ float pm1s[2][8][64];
    __shared__ float pm2s[2][8][64];
    __shared__ int   pi1s[2][8][64];
    __shared__ int   sidx[2][64];

    const int tid = threadIdx.x;
    const int w   = tid >> 6;       // wave 0..15
    const int g   = w >> 3;         // group
    const int nt  = w & 7;          // n-tile
    const int l   = tid & 63;
    const int q   = l & 15;         // token col / B col
    const int h   = l >> 4;         // k-octet / D-subrow
    const int n0  = nt * 16;
    const int tb0 = blockIdx.x * 256;
    const int wsw = w & 7;          // write swizzle (= token&7 for tokens c*16+w)

    const short8* Flds8 = reinterpret_cast<const short8*>(Flds4);
    f32x4* Gl4 = reinterpret_cast<f32x4*>(Glds);

    // ---- persistent W fragments: lane (q,h) holds W[n0+q][ks*32+h*8..+7]
    const short* bt1 = BT + (size_t)g * 16384 + (n0 + q) * 128 + h * 8;
    short8 A1[4], A2[4];
#pragma unroll
    for (int ks = 0; ks < 4; ++ks) {
        A1[ks] = *reinterpret_cast<const short8*>(bt1 + ks * 32);
        A2[ks] = *reinterpret_cast<const short8*>(bt1 + 32768 + ks * 32);
    }
    const f32x4 bv = *reinterpret_cast<const f32x4*>(bl + g * NN + n0 + h * 4);

    // out-write role: 16 threads per token, 4 float4 each
    const int stok = tid >> 4;            // 0..63
    const int sc   = tid & 15;

#pragma unroll
    for (int st = 0; st < 4; ++st) {
        // ---- dense-coalesced stage loads (lane-stride 16B per instruction)
        const float* Freg = features + (size_t)(tb0 + st * 64) * FDIM;
        const float* Greg = gumbel + (size_t)(tb0 + st * 64) * (NG * NN);
        f32x4 Fr[4], Gr[4];
#pragma unroll
        for (int c = 0; c < 4; ++c) {
            Fr[c] = *reinterpret_cast<const f32x4*>(Freg + (c * 1024 + tid) * 4);
            Gr[c] = *reinterpret_cast<const f32x4*>(Greg + (c * 1024 + tid) * 4);
        }

        // ---- exact 2-level bf16 split of the 4 F vectors
        s16x4 SH[4], SL[4];
#pragma unroll
        for (int c = 0; c < 4; ++c) {
#pragma unroll
            for (int e = 0; e < 4; ++e) {
                const unsigned u = __float_as_uint(Fr[c][e]);
                const float hi = __uint_as_float(u & 0xffff0000u);
                SH[c][e] = (short)(u >> 16);
                SL[c][e] = (short)(__float_as_uint(Fr[c][e] - hi) >> 16);
            }
        }

        __syncthreads();   // barrier-A: prev compute done reading Flds/Glds

        // ---- ds_write: token tk=c*16+w, chunk l>>1 (swz ^ tk&7), half l&1
#pragma unroll
        for (int c = 0; c < 4; ++c) {
            const int tk  = c * 16 + w;
            const int pos = tk * 64 + (((l >> 1) ^ wsw) << 1) + (l & 1);
            Flds4[pos]        = SH[c];
            Flds4[4096 + pos] = SL[c];
            Gl4[tk * 64 + (l ^ wsw)] = Gr[c];
        }

        // ---- combine(st-1) in the race-safe slot (between barriers)
        if (st > 0 && tid < 128) {
            const int gg  = tid >> 6;
            const int tok = tid & 63;
            float c1 = pm1s[gg][0][tok], c2 = pm2s[gg][0][tok];
            int   ci = pi1s[gg][0][tok];
#pragma unroll
            for (int p = 1; p < 8; ++p) {
                const float a1 = pm1s[gg][p][tok];
                const float a2 = pm2s[gg][p][tok];
                const int   ai = pi1s[gg][p][tok];
                if (a1 > c1)      { c2 = fmaxf(c1, a2); c1 = a1; ci = ai; }
                else if (a1 < c1) { c2 = fmaxf(c2, a1); }
                else              { c2 = c1; ci = min(ci, ai); }
            }
            const int t = tb0 + (st - 1) * 64 + tok;
            idx_f[(size_t)t * NG + gg] = (float)ci;
            sidx[gg][tok] = ci;
            if (c1 - c2 < TAU) {
                const int p = atomicAdd(flag_count, 1);
                if (p < CAP) flag_list[p] = t * NG + gg;
            }
        }

        __syncthreads();   // barrier-B: staging + sidx visible

        // ---- fused out-write(st-1): coalesced 256B-per-token chunks
        if (st > 0) {
            const int i0 = sidx[0][stok];
            const int i1 = sidx[1][stok];
            const float* c0p = CO + (size_t)i0 * EDIM;
            const float* c1p = CO + (size_t)(NN + i1) * EDIM;
            float* op = out + (size_t)(tb0 + (st - 1) * 64 + stok) * EDIM;
#pragma unroll
            for (int j = 0; j < 4; ++j) {
                const int e4 = sc + j * 16;
                const float4 a  = *reinterpret_cast<const float4*>(c0p + e4 * 4);
                const float4 b2 = *reinterpret_cast<const float4*>(c1p + e4 * 4);
                const float4 bo = *reinterpret_cast<const float4*>(b_out + e4 * 4);
                float4 o;
                o.x = a.x + b2.x + bo.x;
                o.y = a.y + b2.y + bo.y;
                o.z = a.z + b2.z + bo.z;
                o.w = a.w + b2.w + bo.w;
                *reinterpret_cast<float4*>(op + e4 * 4) = o;
            }
        }

        // ---- compute(st): 4 subtiles of 16 tokens (B from LDS, W in regs)
#pragma unroll
        for (int s = 0; s < 4; ++s) {
            const int tok = s * 16 + q;
            f32x4 acc = (f32x4){0.f, 0.f, 0.f, 0.f};
#pragma unroll
            for (int ks = 0; ks < 4; ++ks) {
                const int ci0 = (g * 16 + ks * 4 + h) ^ (q & 7);
                const short8 B1 = Flds8[tok * 32 + ci0];
                const short8 B2 = Flds8[2048 + tok * 32 + ci0];
                acc = __builtin_amdgcn_mfma_f32_16x16x32_bf16(A1[ks], B1, acc, 0, 0, 0);
                acc = __builtin_amdgcn_mfma_f32_16x16x32_bf16(A2[ks], B1, acc, 0, 0, 0);
                acc = __builtin_amdgcn_mfma_f32_16x16x32_bf16(A1[ks], B2, acc, 0, 0, 0);
            }

            const f32x4 gvv = Gl4[tok * 64 + ((g * 32 + nt * 4 + h) ^ (q & 7))];

            float m1 = -3.4e38f, m2 = -3.4e38f;
            int   i1 = 0;
#pragma unroll
            for (int r = 0; r < 4; ++r) {
                const float vv = acc[r] + bv[r] + gvv[r];
                const int   n  = n0 + h * 4 + r;
                if (vv > m1) { m2 = m1; m1 = vv; i1 = n; }
                else         { m2 = fmaxf(m2, vv); }
            }
#pragma unroll
            for (int off = 16; off < 64; off <<= 1) {
                const float om1 = __shfl_xor(m1, off);
                const int   oi1 = __shfl_xor(i1, off);
                const float om2 = __shfl_xor(m2, off);
                if (om1 > m1)      { m2 = fmaxf(m1, om2); m1 = om1; i1 = oi1; }
                else if (om1 < m1) { m2 = fmaxf(m2, om1); }
                else               { m2 = m1; i1 = min(i1, oi1); }
            }
            if (h == 0) {
                pm1s[g][nt][tok] = m1;
                pm2s[g][nt][tok] = m2;
                pi1s[g][nt][tok] = i1;
            }
        }
    }

    // ---- tail: combine + out-write for stage 3
    __syncthreads();
    if (tid < 128) {
        const int gg  = tid >> 6;
        const int tok = tid & 63;
        float c1 = pm1s[gg][0][tok], c2 = pm2s[gg][0][tok];
        int   ci = pi1s[gg][0][tok];
#pragma unroll
        for (int p = 1; p < 8; ++p) {
            const float a1 = pm1s[gg][p][tok];
            const float a2 = pm2s[gg][p][tok];
            const int   ai = pi1s[gg][p][tok];
            if (a1 > c1)      { c2 = fmaxf(c1, a2); c1 = a1; ci = ai; }
            else if (a1 < c1) { c2 = fmaxf(c2, a1); }
            else              { c2 = c1; ci = min(ci, ai); }
        }
        const int t = tb0 + 3 * 64 + tok;
        idx_f[(size_t)t * NG + gg] = (float)ci;
        sidx[gg][tok] = ci;
        if (c1 - c2 < TAU) {
            const int p = atomicAdd(flag_count, 1);
            if (p < CAP) flag_list[p] = t * NG + gg;
        }
    }
    __syncthreads();
    {
        const int i0 = sidx[0][stok];
        const int i1 = sidx[1][stok];
        const float* c0p = CO + (size_t)i0 * EDIM;
        const float* c1p = CO + (size_t)(NN + i1) * EDIM;
        float* op = out + (size_t)(tb0 + 3 * 64 + stok) * EDIM;
#pragma unroll
        for (int j = 0; j < 4; ++j) {
            const int e4 = sc + j * 16;
            const float4 a  = *reinterpret_cast<const float4*>(c0p + e4 * 4);
            const float4 b2 = *reinterpret_cast<const float4*>(c1p + e4 * 4);
            const float4 bo = *reinterpret_cast<const float4*>(b_out + e4 * 4);
            float4 o;
            o.x = a.x + b2.x + bo.x;
            o.y = a.y + b2.y + bo.y;
            o.z = a.z + b2.z + bo.z;
            o.w = a.w + b2.w + bo.w;
            *reinterpret_cast<float4*>(op + e4 * 4) = o;
        }
    }
}

// ---------------------------------------------------------------------------
// Kernel F (fixup): exact sequential-f32 fmaf recompute for flagged (t,g).
// Guarded against corrupt/poison flag entries (uniform branch per block).
// ---------------------------------------------------------------------------
__global__ __launch_bounds__(128) void fixup_kernel(
    const float* __restrict__ features,
    const float* __restrict__ gumbel,
    const float* __restrict__ Wl,         // [2][128 k][128 n]
    const float* __restrict__ bl,
    float* __restrict__ idx_f,
    const int* __restrict__ flag_count,
    const int* __restrict__ flag_list)
{
    __shared__ float sm[2];
    __shared__ int   si[2];
    int total = *flag_count;
    if (total > CAP) total = CAP;
    const int n = threadIdx.x;

    for (int e = blockIdx.x; e < total; e += gridDim.x) {
        const int code = flag_list[e];
        if ((unsigned)code >= (unsigned)(T_TOTAL * NG)) continue;  // uniform
        const int t = code >> 1, g = code & 1;
        const float* fpr = features + (size_t)t * FDIM + g * DDIM;
        const float* wp  = Wl + (size_t)g * DDIM * NN + n;
        float dot = 0.f;
#pragma unroll 8
        for (int k = 0; k < DDIM; ++k) dot = fmaf(fpr[k], wp[(size_t)k * NN], dot);
        const float v = (dot + bl[g * NN + n]) + gumbel[((size_t)t * NG + g) * NN + n];

        float m = v; int bi = n;
#pragma unroll
        for (int off = 1; off < 64; off <<= 1) {
            const float om = __shfl_xor(m, off);
            const int   ob = __shfl_xor(bi, off);
            if (om > m || (om == m && ob < bi)) { m = om; bi = ob; }
        }
        if ((n & 63) == 0) { sm[n >> 6] = m; si[n >> 6] = bi; }
        __syncthreads();
        if (n == 0) {
            const float mA = sm[0], mB = sm[1];
            const int bA = si[0], bB = si[1];
            const int best = (mB > mA || (mB == mA && bB < bA)) ? bB : bA;
            idx_f[code] = (float)best;
        }
        __syncthreads();
    }
}

// ---------------------------------------------------------------------------
// Kernel X (outfix): rewrite out rows for flagged tokens from FINAL indices.
// Guarded against corrupt/poison flag entries and indices.
// ---------------------------------------------------------------------------
__global__ __launch_bounds__(64) void outfix_kernel(
    const float* __restrict__ CO,
    const float* __restrict__ b_out,
    const float* __restrict__ idx_f,
    const int* __restrict__ flag_count,
    const int* __restrict__ flag_list,
    float* __restrict__ out)
{
    int total = *flag_count;
    if (total > CAP) total = CAP;
    const int c = threadIdx.x;    // 0..63 float4 slots

    for (int e = blockIdx.x; e < total; e += gridDim.x) {
        const int code = flag_list[e];
        if ((unsigned)code >= (unsigned)(T_TOTAL * NG)) continue;  // uniform
        const int t  = code >> 1;
        const int i0 = ((int)idx_f[t * NG + 0]) & 127;
        const int i1 = ((int)idx_f[t * NG + 1]) & 127;
        const float4 a  = *reinterpret_cast<const float4*>(CO + (size_t)i0 * EDIM + c * 4);
        const float4 b2 = *reinterpret_cast<const float4*>(CO + (size_t)(NN + i1) * EDIM + c * 4);
        const float4 bo = *reinterpret_cast<const float4*>(b_out + c * 4);
        float4 o;
        o.x = a.x + b2.x + bo.x;
        o.y = a.y + b2.y + bo.y;
        o.z = a.z + b2.z + bo.z;
        o.w = a.w + b2.w + bo.w;
        *reinterpret_cast<float4*>(out + (size_t)t * EDIM + c * 4) = o;
    }
}

// ---------------------------------------------------------------------------
extern "C" void kernel_launch(void* const* d_in, const int* in_sizes, int n_in,
                              void* d_out, int out_size, void* d_ws, size_t ws_size,
                              hipStream_t stream) {
    const float* features  = (const float*)d_in[0];  // [32,4096,256]
    const float* gumbel    = (const float*)d_in[1];  // [32,4096,2,128]
    const float* Wl        = (const float*)d_in[2];  // [2,128,128]
    const float* bl        = (const float*)d_in[3];  // [2,128]
    const float* codebooks = (const float*)d_in[4];  // [2,128,128]
    const float* W_out     = (const float*)d_in[5];  // [256,256]
    const float* b_out     = (const float*)d_in[6];  // [256]

    float* out   = (float*)d_out;                    // [T,256]
    float* idx_f = out + (size_t)T_TOTAL * EDIM;     // [T,2] float-encoded indices

    // ws layout: CO (256KB) | BT (128KB) | flag_count (pad 256B) | flag_list (64KB)
    char* ws = (char*)d_ws;
    float* CO         = (float*)ws;                        // 262144 B
    short* BT         = (short*)(ws + 262144);             // 131072 B
    int*   flag_count = (int*)(ws + 262144 + 131072);      // @393216
    int*   flag_list  = (int*)(ws + 393216 + 256);         // @393472, 64KB

    prep_kernel<<<NG * NN, 256, 0, stream>>>(codebooks, W_out, Wl, CO, BT, flag_count);
    pq_v19_kernel<<<T_TOTAL / 256, 1024, 0, stream>>>(
        features, gumbel, BT, bl, CO, b_out, out, idx_f, flag_count, flag_list);
    fixup_kernel<<<1024, 128, 0, stream>>>(
        features, gumbel, Wl, bl, idx_f, flag_count, flag_list);
    outfix_kernel<<<1024, 64, 0, stream>>>(
        CO, b_out, idx_f, flag_count, flag_list, out);
}

// Round 19
// 136.734 us; speedup vs baseline: 1.0696x; 1.0696x over previous
//
#include <hip/hip_runtime.h>

// Problem dims (fixed by reference)
#define T_TOTAL (32 * 4096)   // B*S = 131072 tokens
#define FDIM 256
#define NG 2                  // groups
#define NN 128                // entries per group
#define DDIM 128              // group dim
#define EDIM 256              // embed dim

#define TAU 0.004f            // bf16x3-vs-f32 safety margin for argmax gap
#define CAP 16384             // max flagged (t,g) entries (expected ~1k)

typedef __attribute__((ext_vector_type(4))) float f32x4;
typedef __attribute__((ext_vector_type(8))) short short8;

// direct HBM->LDS DMA, 16B per lane, dest = wave-uniform base + lane*16
__device__ __forceinline__ void gl2lds(const float* gsrc, float* ldst) {
    __builtin_amdgcn_global_load_lds(
        (const __attribute__((address_space(1))) unsigned int*)gsrc,
        (__attribute__((address_space(3))) unsigned int*)ldst,
        16, 0, 0);
}

// ---------------------------------------------------------------------------
// Kernel P (prep): CO = codebooks @ W_out slices ; BT = split-bf16 W^T ;
// zero flag counter. One block per (g,n) = 256 blocks x 256 threads.
// ---------------------------------------------------------------------------
__global__ __launch_bounds__(256) void prep_kernel(
    const float* __restrict__ codebooks,  // [2][128][128]
    const float* __restrict__ W_out,      // [256][256]
    const float* __restrict__ Wl,         // [2][128 k][128 n]
    float* __restrict__ CO,               // [2][128][256]
    short* __restrict__ BT,               // [2 lev][2 g][128 n][128 k]
    int* __restrict__ flag_count)
{
    const int gn  = blockIdx.x;           // g*128 + n
    const int g   = gn >> 7;
    const int tid = threadIdx.x;
    __shared__ float cb[DDIM];
    if (tid < DDIM) cb[tid] = codebooks[gn * DDIM + tid];
    if (tid >= 128) {
        const int k = tid - 128;
        const int n = gn & 127;
        const float x = Wl[((size_t)g * DDIM + k) * NN + n];
        const unsigned u = __float_as_uint(x);
        const float hi = __uint_as_float(u & 0xffff0000u);
        const unsigned u2 = __float_as_uint(x - hi);   // exact residual
        BT[(size_t)g * 16384 + n * 128 + k] = (short)(u >> 16);
        BT[32768 + (size_t)g * 16384 + n * 128 + k] = (short)(u2 >> 16);
    }
    if (gn == 0 && tid == 0) *flag_count = 0;
    __syncthreads();
    float acc = 0.f;
    const float* wcol = W_out + (g * DDIM) * EDIM + tid;
#pragma unroll 4
    for (int d = 0; d < DDIM; ++d) acc += cb[d] * wcol[d * EDIM];
    CO[gn * EDIM + tid] = acc;
}

// ---------------------------------------------------------------------------
// Kernel M (main v20): global_load_lds staging (the never-tried guide lever).
// Block = 512 thr = 8 waves = 8 n-tiles, ONE group, 256 tokens over 8 stages
// of 32. Per stage: [barrier: DMA(st) drained + compute(st-1) done] ->
// issue DMA(st+1) into other buffer -> combine(st-1) [tid<32, pm double-buf]
// -> compute(st): per subtile, ds_read f32 fragment (swizzled), SPLIT to
// bf16x2 in-register, 3 MFMAs vs W-in-regs; gumbel read from LDS at epilogue.
// Swizzle per rule #21: linear LDS dest, global SOURCE pre-swizzled
// (chunk ^= row&7), swizzled ds_read. One barrier per stage (m97 schedule);
// loads for st+1 are in flight across compute(st), drained free at barrier.
// Numerics byte-identical to r5-r18 (same split, TAU, argmax, fixup).
// ---------------------------------------------------------------------------
__global__ __launch_bounds__(512) void pq_v20_kernel(
    const float* __restrict__ features,   // [T][256]
    const float* __restrict__ gumbel,     // [T][2][128]
    const short* __restrict__ BT,         // [2 lev][2 g][128 n][128 k]
    const float* __restrict__ bl,         // [2][128]
    float* __restrict__ idx_f,            // [T][2] float-encoded indices
    int* __restrict__ flag_count,
    int* __restrict__ flag_list)
{
    __shared__ __align__(16) float Fb[2][32 * 128];   // 2 x 16 KB
    __shared__ __align__(16) float Gb[2][32 * 128];   // 2 x 16 KB
    __shared__ float pm1[2][8][32];
    __shared__ float pm2[2][8][32];
    __shared__ int   pi1[2][8][32];

    const int tid = threadIdx.x;
    const int g   = blockIdx.x & 1;
    const int gb  = blockIdx.x >> 1;      // 0..511
    const int w   = tid >> 6;             // wave = n-tile 0..7
    const int l   = tid & 63;
    const int q   = l & 15;               // token col / B col
    const int h   = l >> 4;               // k-octet / D-subrow
    const int n0  = w * 16;
    const int tb0 = gb * 256;

    // ---- persistent W fragments: lane (q,h) holds W[n0+q][ks*32+h*8..+7]
    const short* bt1 = BT + (size_t)g * 16384 + (n0 + q) * 128 + h * 8;
    short8 A1[4], A2[4];
#pragma unroll
    for (int ks = 0; ks < 4; ++ks) {
        A1[ks] = *reinterpret_cast<const short8*>(bt1 + ks * 32);
        A2[ks] = *reinterpret_cast<const short8*>(bt1 + 32768 + ks * 32);
    }
    const f32x4 bv = *reinterpret_cast<const f32x4*>(bl + g * NN + n0 + h * 4);

    // ---- DMA staging addresses: wave issues 2 F + 2 G instructions/stage.
    // Instr idx = w*2+j moves rows {2idx, 2idx+1} (64 lanes x 16B = 1 KB).
    // lane: row r = 2*idx + (l>>5), chunk c = l&31; SOURCE chunk = c ^ (r&7)
    // so LDS[r][c] = global[r][c^(r&7)] with a LINEAR dest (rule #21).
    const int r0 = 4 * w + (l >> 5);      // rows for j=0
    const int r1 = r0 + 2;                // rows for j=1
    const int cc = l & 31;
    const float* fsrc0 = features + (size_t)(tb0 + r0) * FDIM + g * DDIM + ((cc ^ (r0 & 7)) << 2);
    const float* fsrc1 = features + (size_t)(tb0 + r1) * FDIM + g * DDIM + ((cc ^ (r1 & 7)) << 2);
    const float* gsrc0 = gumbel + ((size_t)(tb0 + r0) * NG + g) * NN + ((cc ^ (r0 & 7)) << 2);
    const float* gsrc1 = gumbel + ((size_t)(tb0 + r1) * NG + g) * NN + ((cc ^ (r1 & 7)) << 2);

#define STAGE(BUF, ST) do {                                                 \
        const size_t fo = (size_t)(ST) * 32 * FDIM;                         \
        const size_t go = (size_t)(ST) * 32 * (NG * NN);                    \
        gl2lds(fsrc0 + fo, &Fb[BUF][(w * 2) * 256]);                        \
        gl2lds(fsrc1 + fo, &Fb[BUF][(w * 2 + 1) * 256]);                    \
        gl2lds(gsrc0 + go, &Gb[BUF][(w * 2) * 256]);                        \
        gl2lds(gsrc1 + go, &Gb[BUF][(w * 2 + 1) * 256]);                    \
    } while (0)

    // ---- prologue: DMA stage 0 into buffer 0
    STAGE(0, 0);

    for (int st = 0; st < 8; ++st) {
        __syncthreads();   // drains vmcnt: DMA(st) complete; compute(st-1) done

        const int cur = st & 1;
        if (st < 7) STAGE(cur ^ 1, st + 1);   // in flight across compute(st)

        // ---- combine(st-1): pm double-buffered, race-free without 2nd barrier
        if (st > 0 && tid < 32) {
            const int bufp = (st - 1) & 1;
            float c1 = pm1[bufp][0][tid], c2 = pm2[bufp][0][tid];
            int   ci = pi1[bufp][0][tid];
#pragma unroll
            for (int p = 1; p < 8; ++p) {
                const float a1 = pm1[bufp][p][tid];
                const float a2 = pm2[bufp][p][tid];
                const int   ai = pi1[bufp][p][tid];
                if (a1 > c1)      { c2 = fmaxf(c1, a2); c1 = a1; ci = ai; }
                else if (a1 < c1) { c2 = fmaxf(c2, a1); }
                else              { c2 = c1; ci = min(ci, ai); }
            }
            const int t = tb0 + (st - 1) * 32 + tid;
            idx_f[(size_t)t * NG + g] = (float)ci;
            if (c1 - c2 < TAU) {
                const int p = atomicAdd(flag_count, 1);
                if (p < CAP) flag_list[p] = t * NG + g;
            }
        }

        // ---- compute(st): 2 subtiles of 16 tokens
#pragma unroll
        for (int s = 0; s < 2; ++s) {
            const int tl = s * 16 + q;        // token-local 0..31
            const int sw = tl & 7;
            f32x4 acc = (f32x4){0.f, 0.f, 0.f, 0.f};
#pragma unroll
            for (int ks = 0; ks < 4; ++ks) {
                // f32 fragment (8 floats) via two swizzled 16B LDS reads
                const f32x4 fa = *reinterpret_cast<const f32x4*>(
                    &Fb[cur][tl * 128 + (((ks * 8 + h * 2)     ^ sw) << 2)]);
                const f32x4 fb = *reinterpret_cast<const f32x4*>(
                    &Fb[cur][tl * 128 + (((ks * 8 + h * 2 + 1) ^ sw) << 2)]);
                // exact 2-level bf16 split (same numerics as all passing rounds)
                short8 B1, B2;
#pragma unroll
                for (int e = 0; e < 4; ++e) {
                    unsigned u = __float_as_uint(fa[e]);
                    float hi = __uint_as_float(u & 0xffff0000u);
                    B1[e] = (short)(u >> 16);
                    B2[e] = (short)(__float_as_uint(fa[e] - hi) >> 16);
                    u = __float_as_uint(fb[e]);
                    hi = __uint_as_float(u & 0xffff0000u);
                    B1[4 + e] = (short)(u >> 16);
                    B2[4 + e] = (short)(__float_as_uint(fb[e] - hi) >> 16);
                }
                acc = __builtin_amdgcn_mfma_f32_16x16x32_bf16(A1[ks], B1, acc, 0, 0, 0);
                acc = __builtin_amdgcn_mfma_f32_16x16x32_bf16(A2[ks], B1, acc, 0, 0, 0);
                acc = __builtin_amdgcn_mfma_f32_16x16x32_bf16(A1[ks], B2, acc, 0, 0, 0);
            }

            // gumbel for this lane's 4 n-values, from LDS (swizzled chunk)
            const f32x4 gvv = *reinterpret_cast<const f32x4*>(
                &Gb[cur][tl * 128 + (((w * 4 + h) ^ sw) << 2)]);

            float m1 = -3.4e38f, m2 = -3.4e38f;
            int   i1 = 0;
#pragma unroll
            for (int r = 0; r < 4; ++r) {
                const float vv = acc[r] + bv[r] + gvv[r];
                const int   n  = n0 + h * 4 + r;
                if (vv > m1) { m2 = m1; m1 = vv; i1 = n; }
                else         { m2 = fmaxf(m2, vv); }
            }
#pragma unroll
            for (int off = 16; off < 64; off <<= 1) {
                const float om1 = __shfl_xor(m1, off);
                const int   oi1 = __shfl_xor(i1, off);
                const float om2 = __shfl_xor(m2, off);
                if (om1 > m1)      { m2 = fmaxf(m1, om2); m1 = om1; i1 = oi1; }
                else if (om1 < m1) { m2 = fmaxf(m2, om1); }
                else               { m2 = m1; i1 = min(i1, oi1); }
            }
            if (h == 0) {
                pm1[cur][w][tl] = m1;
                pm2[cur][w][tl] = m2;
                pi1[cur][w][tl] = i1;
            }
        }
    }
#undef STAGE

    // ---- tail: combine stage 7
    __syncthreads();
    if (tid < 32) {
        float c1 = pm1[1][0][tid], c2 = pm2[1][0][tid];
        int   ci = pi1[1][0][tid];
#pragma unroll
        for (int p = 1; p < 8; ++p) {
            const float a1 = pm1[1][p][tid];
            const float a2 = pm2[1][p][tid];
            const int   ai = pi1[1][p][tid];
            if (a1 > c1)      { c2 = fmaxf(c1, a2); c1 = a1; ci = ai; }
            else if (a1 < c1) { c2 = fmaxf(c2, a1); }
            else              { c2 = c1; ci = min(ci, ai); }
        }
        const int t = tb0 + 7 * 32 + tid;
        idx_f[(size_t)t * NG + g] = (float)ci;
        if (c1 - c2 < TAU) {
            const int p = atomicAdd(flag_count, 1);
            if (p < CAP) flag_list[p] = t * NG + g;
        }
    }
}

// ---------------------------------------------------------------------------
// Kernel F (fixup): exact sequential-f32 fmaf recompute for flagged (t,g).
// ---------------------------------------------------------------------------
__global__ __launch_bounds__(128) void fixup_kernel(
    const float* __restrict__ features,
    const float* __restrict__ gumbel,
    const float* __restrict__ Wl,         // [2][128 k][128 n]
    const float* __restrict__ bl,
    float* __restrict__ idx_f,
    const int* __restrict__ flag_count,
    const int* __restrict__ flag_list)
{
    __shared__ float sm[2];
    __shared__ int   si[2];
    int total = *flag_count;
    if (total > CAP) total = CAP;
    const int n = threadIdx.x;

    for (int e = blockIdx.x; e < total; e += gridDim.x) {
        const int code = flag_list[e];
        if ((unsigned)code >= (unsigned)(T_TOTAL * NG)) continue;  // uniform guard
        const int t = code >> 1, g = code & 1;
        const float* fpr = features + (size_t)t * FDIM + g * DDIM;
        const float* wp  = Wl + (size_t)g * DDIM * NN + n;
        float dot = 0.f;
#pragma unroll 8
        for (int k = 0; k < DDIM; ++k) dot = fmaf(fpr[k], wp[(size_t)k * NN], dot);
        const float v = (dot + bl[g * NN + n]) + gumbel[((size_t)t * NG + g) * NN + n];

        float m = v; int bi = n;
#pragma unroll
        for (int off = 1; off < 64; off <<= 1) {
            const float om = __shfl_xor(m, off);
            const int   ob = __shfl_xor(bi, off);
            if (om > m || (om == m && ob < bi)) { m = om; bi = ob; }
        }
        if ((n & 63) == 0) { sm[n >> 6] = m; si[n >> 6] = bi; }
        __syncthreads();
        if (n == 0) {
            const float mA = sm[0], mB = sm[1];
            const int bA = si[0], bB = si[1];
            const int best = (mB > mA || (mB == mA && bB < bA)) ? bB : bA;
            idx_f[code] = (float)best;
        }
        __syncthreads();
    }
}

// ---------------------------------------------------------------------------
// Kernel C: out[t][e] = CO[0][i0][e] + CO[1][i1][e] + b_out[e]
// (runs AFTER fixup, so it reads final indices — no outfix needed)
// ---------------------------------------------------------------------------
__global__ __launch_bounds__(256) void out_kernel(
    const float* __restrict__ CO,      // [2][128][256]
    const float* __restrict__ b_out,   // [256]
    const float* __restrict__ idx_f,   // [T][2] float-encoded
    float* __restrict__ out)           // [T][256]
{
    const int tid = threadIdx.x;
    const int e4  = tid & 63;    // float4 index in e
    const int ts  = tid >> 6;    // 0..3
    const int tbase = blockIdx.x * 16;
    const float4 b = *reinterpret_cast<const float4*>(b_out + e4 * 4);

#pragma unroll
    for (int it = 0; it < 4; ++it) {
        const int t  = tbase + it * 4 + ts;
        const int i0 = ((int)idx_f[t * NG + 0]) & 127;
        const int i1 = ((int)idx_f[t * NG + 1]) & 127;
        const float4 c0 = *reinterpret_cast<const float4*>(CO + (size_t)i0 * EDIM + e4 * 4);
        const float4 c1 = *reinterpret_cast<const float4*>(CO + (size_t)(NN + i1) * EDIM + e4 * 4);
        float4 o;
        o.x = c0.x + c1.x + b.x;
        o.y = c0.y + c1.y + b.y;
        o.z = c0.z + c1.z + b.z;
        o.w = c0.w + c1.w + b.w;
        *reinterpret_cast<float4*>(out + (size_t)t * EDIM + e4 * 4) = o;
    }
}

// ---------------------------------------------------------------------------
extern "C" void kernel_launch(void* const* d_in, const int* in_sizes, int n_in,
                              void* d_out, int out_size, void* d_ws, size_t ws_size,
                              hipStream_t stream) {
    const float* features  = (const float*)d_in[0];  // [32,4096,256]
    const float* gumbel    = (const float*)d_in[1];  // [32,4096,2,128]
    const float* Wl        = (const float*)d_in[2];  // [2,128,128]
    const float* bl        = (const float*)d_in[3];  // [2,128]
    const float* codebooks = (const float*)d_in[4];  // [2,128,128]
    const float* W_out     = (const float*)d_in[5];  // [256,256]
    const float* b_out     = (const float*)d_in[6];  // [256]

    float* out   = (float*)d_out;                    // [T,256]
    float* idx_f = out + (size_t)T_TOTAL * EDIM;     // [T,2] float-encoded indices

    // ws layout: CO (256KB) | BT (128KB) | flag_count (pad 256B) | flag_list (64KB)
    char* ws = (char*)d_ws;
    float* CO         = (float*)ws;                        // 262144 B
    short* BT         = (short*)(ws + 262144);             // 131072 B
    int*   flag_count = (int*)(ws + 262144 + 131072);      // @393216
    int*   flag_list  = (int*)(ws + 393216 + 256);         // @393472, 64KB

    prep_kernel<<<NG * NN, 256, 0, stream>>>(codebooks, W_out, Wl, CO, BT, flag_count);
    pq_v20_kernel<<<1024, 512, 0, stream>>>(
        features, gumbel, BT, bl, idx_f, flag_count, flag_list);
    fixup_kernel<<<1024, 128, 0, stream>>>(
        features, gumbel, Wl, bl, idx_f, flag_count, flag_list);
    out_kernel<<<T_TOTAL / 16, 256, 0, stream>>>(CO, b_out, idx_f, out);
}

// Round 20
// 118.730 us; speedup vs baseline: 1.2318x; 1.1516x over previous
//
#include <hip/hip_runtime.h>

// Problem dims (fixed by reference)
#define T_TOTAL (32 * 4096)   // B*S = 131072 tokens
#define FDIM 256
#define NG 2                  // groups
#define NN 128                // entries per group
#define DDIM 128              // group dim
#define EDIM 256              // embed dim

#define TAU 0.004f            // bf16x3-vs-f32 safety margin for argmax gap
#define CAP 16384             // max flagged (t,g) entries (expected ~1k)

typedef __attribute__((ext_vector_type(4))) float f32x4;
typedef __attribute__((ext_vector_type(8))) short short8;

// ---------------------------------------------------------------------------
// Kernel P (prep): CO = codebooks @ W_out slices ; BT = split-bf16 W^T ;
// zero flag counter. One block per (g,n) = 256 blocks x 256 threads.
// ---------------------------------------------------------------------------
__global__ __launch_bounds__(256) void prep_kernel(
    const float* __restrict__ codebooks,  // [2][128][128]
    const float* __restrict__ W_out,      // [256][256]
    const float* __restrict__ Wl,         // [2][128 k][128 n]
    float* __restrict__ CO,               // [2][128][256]
    short* __restrict__ BT,               // [2 lev][2 g][128 n][128 k]
    int* __restrict__ flag_count)
{
    const int gn  = blockIdx.x;           // g*128 + n
    const int g   = gn >> 7;
    const int tid = threadIdx.x;
    __shared__ float cb[DDIM];
    if (tid < DDIM) cb[tid] = codebooks[gn * DDIM + tid];
    if (tid >= 128) {
        const int k = tid - 128;
        const int n = gn & 127;
        const float x = Wl[((size_t)g * DDIM + k) * NN + n];
        const unsigned u = __float_as_uint(x);
        const float hi = __uint_as_float(u & 0xffff0000u);
        const unsigned u2 = __float_as_uint(x - hi);   // exact residual
        BT[(size_t)g * 16384 + n * 128 + k] = (short)(u >> 16);
        BT[32768 + (size_t)g * 16384 + n * 128 + k] = (short)(u2 >> 16);
    }
    if (gn == 0 && tid == 0) *flag_count = 0;
    __syncthreads();
    float acc = 0.f;
    const float* wcol = W_out + (g * DDIM) * EDIM + tid;
#pragma unroll 4
    for (int d = 0; d < DDIM; ++d) acc += cb[d] * wcol[d * EDIM];
    CO[gn * EDIM + tid] = acc;
}

// ---------------------------------------------------------------------------
// Kernel M (main, r15-best): W both split levels in 64 KB LDS (swizzled,
// conflict-free), barrier-free main loop, 8 waves x 16 tokens x 128 n,
// asm-pinned global loads with manual vmcnt placement:
//   [vmcnt(0)] split F(it) -> issue GA(it) -> MFMA (LDS-only, ~2.5k cy)
//   -> [vmcnt(0)] -> issue F(it+1) -> epilogue (GA consumed, F in flight)
// Best-measured configuration of the session (main ~97us, total 118.7us).
// Session record: coalescing fixes (r16-r18), DMA staging (r19), occupancy
// boosts (r6-r8), and vmcnt scheduling (r13-r14) all failed to beat it —
// the residual is a latency-structure plateau with no pipe >40%.
// ---------------------------------------------------------------------------
__global__ __launch_bounds__(512) void pq_v16_kernel(
    const float* __restrict__ features,   // [T][256]
    const float* __restrict__ gumbel,     // [T][2][128]
    const short* __restrict__ BT,         // [2 lev][2 g][128 n][128 k]
    const float* __restrict__ bl,         // [2][128]
    float* __restrict__ idx_f,            // [T][2] float-encoded indices
    int* __restrict__ flag_count,
    int* __restrict__ flag_list)
{
    __shared__ short8 Wlds[4096];   // 64 KB: [lev][n][slot ^ (n&15)]
    __shared__ float  bl_s[NN];

    const int tid = threadIdx.x;
    const int g   = blockIdx.x & 1;
    const int gb  = blockIdx.x >> 1;    // 0..255
    const int w   = tid >> 6;           // wave 0..7
    const int l   = tid & 63;
    const int q   = l & 15;             // token slot / A row low bits
    const int h   = l >> 4;             // k-chunk selector / n-subrow

    // ---- stage W (both levels) for this group into LDS, swizzled
    {
        const short8* src = reinterpret_cast<const short8*>(BT) + g * 2048;
#pragma unroll
        for (int i = 0; i < 8; ++i) {
            const int S   = tid + i * 512;       // 0..4095
            const int lev = S >> 11;
            const int n   = (S >> 4) & 127;
            const int sl  = S & 15;
            Wlds[lev * 2048 + n * 16 + (sl ^ (n & 15))] = src[lev * 4096 + n * 16 + sl];
        }
        if (tid < NN) bl_s[tid] = bl[g * NN + tid];
    }
    __syncthreads();

    const int t0 = gb * 512 + w * 16 + q;    // lane's token at it=0 (+128/iter)
    const float* fbase = features + (size_t)t0 * FDIM + g * DDIM + h * 8;
    const float* gbase = gumbel + ((size_t)t0 * NG + g) * NN + h * 4;

    f32x4 F[8], GA[8];

#define GLOAD(dst, ptr) \
    asm volatile("global_load_dwordx4 %0, %1, off" : "=v"(dst) : "v"(ptr))
#define VWAIT() do { \
    asm volatile("s_waitcnt vmcnt(0)" ::: "memory"); \
    __builtin_amdgcn_sched_barrier(0); } while (0)

    // ---- prologue: issue F(0)
#pragma unroll
    for (int j = 0; j < 8; ++j)
        GLOAD(F[j], fbase + (j >> 1) * 32 + (j & 1) * 4);

#define PQ_IT(IT)                                                               \
    {                                                                           \
        VWAIT();   /* F(IT) landed (was in flight across prev epilogue) */      \
        /* issue GA(IT): consumed after the MFMA phase */                       \
        {                                                                       \
            const float* gp = gbase + (size_t)(IT) * 128 * NG * NN;             \
            _Pragma("unroll")                                                   \
            for (int nt = 0; nt < 8; ++nt)                                      \
                GLOAD(GA[nt], gp + nt * 16);                                    \
        }                                                                       \
        f32x4 acc[8];                                                           \
        _Pragma("unroll")                                                       \
        for (int nt = 0; nt < 8; ++nt) acc[nt] = (f32x4){0.f, 0.f, 0.f, 0.f};   \
        _Pragma("unroll")                                                       \
        for (int ks = 0; ks < 4; ++ks) {                                        \
            short8 B1, B2;                                                      \
            _Pragma("unroll")                                                   \
            for (int e = 0; e < 4; ++e) {                                       \
                const unsigned ua = __float_as_uint(F[2 * ks][e]);              \
                const float ha = __uint_as_float(ua & 0xffff0000u);             \
                const unsigned ra = __float_as_uint(F[2 * ks][e] - ha);         \
                B1[e] = (short)(ua >> 16);                                      \
                B2[e] = (short)(ra >> 16);                                      \
                const unsigned ub = __float_as_uint(F[2 * ks + 1][e]);          \
                const float hb = __uint_as_float(ub & 0xffff0000u);             \
                const unsigned rb = __float_as_uint(F[2 * ks + 1][e] - hb);     \
                B1[4 + e] = (short)(ub >> 16);                                  \
                B2[4 + e] = (short)(rb >> 16);                                  \
            }                                                                   \
            _Pragma("unroll")                                                   \
            for (int nt = 0; nt < 8; ++nt) {                                    \
                const int base = (nt * 16 + q) * 16 + ((ks * 4 + h) ^ q);       \
                const short8 A1 = Wlds[base];                                   \
                const short8 A2 = Wlds[2048 + base];                            \
                acc[nt] = __builtin_amdgcn_mfma_f32_16x16x32_bf16(A1, B1, acc[nt], 0, 0, 0); \
                acc[nt] = __builtin_amdgcn_mfma_f32_16x16x32_bf16(A2, B1, acc[nt], 0, 0, 0); \
                acc[nt] = __builtin_amdgcn_mfma_f32_16x16x32_bf16(A1, B2, acc[nt], 0, 0, 0); \
            }                                                                   \
        }                                                                       \
        VWAIT();   /* GA(IT) landed (was in flight across the MFMA phase) */    \
        /* issue F(IT+1): in flight across the epilogue below */                \
        if ((IT) < 3) {                                                         \
            const float* fp = fbase + (size_t)((IT) + 1) * 128 * FDIM;          \
            _Pragma("unroll")                                                   \
            for (int j = 0; j < 8; ++j)                                         \
                GLOAD(F[j], fp + (j >> 1) * 32 + (j & 1) * 4);                  \
        }                                                                       \
        /* epilogue: +bias(LDS) +gumbel(regs), top-2 argmax */                  \
        float m1 = -3.4e38f, m2 = -3.4e38f;                                     \
        int   i1 = 0;                                                           \
        _Pragma("unroll")                                                       \
        for (int nt = 0; nt < 8; ++nt) {                                        \
            const f32x4 bvr = *reinterpret_cast<const f32x4*>(&bl_s[nt * 16 + h * 4]); \
            _Pragma("unroll")                                                   \
            for (int r = 0; r < 4; ++r) {                                       \
                const float vv = acc[nt][r] + bvr[r] + GA[nt][r];               \
                const int   n  = nt * 16 + h * 4 + r;                           \
                if (vv > m1) { m2 = m1; m1 = vv; i1 = n; }                      \
                else         { m2 = fmaxf(m2, vv); }                            \
            }                                                                   \
        }                                                                       \
        _Pragma("unroll")                                                       \
        for (int off = 16; off < 64; off <<= 1) {                               \
            const float om1 = __shfl_xor(m1, off);                              \
            const int   oi1 = __shfl_xor(i1, off);                              \
            const float om2 = __shfl_xor(m2, off);                              \
            if (om1 > m1)      { m2 = fmaxf(m1, om2); m1 = om1; i1 = oi1; }     \
            else if (om1 < m1) { m2 = fmaxf(m2, om1); }                         \
            else               { m2 = m1; i1 = min(i1, oi1); }                  \
        }                                                                       \
        if (h == 0) {                                                           \
            const int t = t0 + (IT) * 128;                                      \
            idx_f[(size_t)t * NG + g] = (float)i1;                              \
            if (m1 - m2 < TAU) {                                                \
                const int p = atomicAdd(flag_count, 1);                         \
                if (p < CAP) flag_list[p] = t * NG + g;                         \
            }                                                                   \
        }                                                                       \
    }

    PQ_IT(0)
    PQ_IT(1)
    PQ_IT(2)
    PQ_IT(3)
#undef PQ_IT
#undef GLOAD
#undef VWAIT
}

// ---------------------------------------------------------------------------
// Kernel F (fixup): exact sequential-f32 fmaf recompute for flagged (t,g).
// ---------------------------------------------------------------------------
__global__ __launch_bounds__(128) void fixup_kernel(
    const float* __restrict__ features,
    const float* __restrict__ gumbel,
    const float* __restrict__ Wl,         // [2][128 k][128 n]
    const float* __restrict__ bl,
    float* __restrict__ idx_f,
    const int* __restrict__ flag_count,
    const int* __restrict__ flag_list)
{
    __shared__ float sm[2];
    __shared__ int   si[2];
    int total = *flag_count;
    if (total > CAP) total = CAP;
    const int n = threadIdx.x;

    for (int e = blockIdx.x; e < total; e += gridDim.x) {
        const int code = flag_list[e];
        const int t = code >> 1, g = code & 1;
        const float* fpr = features + (size_t)t * FDIM + g * DDIM;
        const float* wp  = Wl + (size_t)g * DDIM * NN + n;
        float dot = 0.f;
#pragma unroll 8
        for (int k = 0; k < DDIM; ++k) dot = fmaf(fpr[k], wp[(size_t)k * NN], dot);
        const float v = (dot + bl[g * NN + n]) + gumbel[((size_t)t * NG + g) * NN + n];

        float m = v; int bi = n;
#pragma unroll
        for (int off = 1; off < 64; off <<= 1) {
            const float om = __shfl_xor(m, off);
            const int   ob = __shfl_xor(bi, off);
            if (om > m || (om == m && ob < bi)) { m = om; bi = ob; }
        }
        if ((n & 63) == 0) { sm[n >> 6] = m; si[n >> 6] = bi; }
        __syncthreads();
        if (n == 0) {
            const float mA = sm[0], mB = sm[1];
            const int bA = si[0], bB = si[1];
            const int best = (mB > mA || (mB == mA && bB < bA)) ? bB : bA;
            idx_f[code] = (float)best;
        }
        __syncthreads();
    }
}

// ---------------------------------------------------------------------------
// Kernel C: out[t][e] = CO[0][i0][e] + CO[1][i1][e] + b_out[e]
// (runs AFTER fixup — reads final indices)
// ---------------------------------------------------------------------------
__global__ __launch_bounds__(256) void out_kernel(
    const float* __restrict__ CO,      // [2][128][256]
    const float* __restrict__ b_out,   // [256]
    const float* __restrict__ idx_f,   // [T][2] float-encoded
    float* __restrict__ out)           // [T][256]
{
    const int tid = threadIdx.x;
    const int e4  = tid & 63;    // float4 index in e
    const int ts  = tid >> 6;    // 0..3
    const int tbase = blockIdx.x * 16;
    const float4 b = *reinterpret_cast<const float4*>(b_out + e4 * 4);

#pragma unroll
    for (int it = 0; it < 4; ++it) {
        const int t  = tbase + it * 4 + ts;
        const int i0 = (int)idx_f[t * NG + 0];
        const int i1 = (int)idx_f[t * NG + 1];
        const float4 c0 = *reinterpret_cast<const float4*>(CO + (size_t)i0 * EDIM + e4 * 4);
        const float4 c1 = *reinterpret_cast<const float4*>(CO + (size_t)(NN + i1) * EDIM + e4 * 4);
        float4 o;
        o.x = c0.x + c1.x + b.x;
        o.y = c0.y + c1.y + b.y;
        o.z = c0.z + c1.z + b.z;
        o.w = c0.w + c1.w + b.w;
        *reinterpret_cast<float4*>(out + (size_t)t * EDIM + e4 * 4) = o;
    }
}

// ---------------------------------------------------------------------------
extern "C" void kernel_launch(void* const* d_in, const int* in_sizes, int n_in,
                              void* d_out, int out_size, void* d_ws, size_t ws_size,
                              hipStream_t stream) {
    const float* features  = (const float*)d_in[0];  // [32,4096,256]
    const float* gumbel    = (const float*)d_in[1];  // [32,4096,2,128]
    const float* Wl        = (const float*)d_in[2];  // [2,128,128]
    const float* bl        = (const float*)d_in[3];  // [2,128]
    const float* codebooks = (const float*)d_in[4];  // [2,128,128]
    const float* W_out     = (const float*)d_in[5];  // [256,256]
    const float* b_out     = (const float*)d_in[6];  // [256]

    float* out   = (float*)d_out;                    // [T,256]
    float* idx_f = out + (size_t)T_TOTAL * EDIM;     // [T,2] float-encoded indices

    // ws layout: CO (256KB) | BT (128KB) | flag_count (pad 256B) | flag_list (64KB)
    char* ws = (char*)d_ws;
    float* CO         = (float*)ws;                        // 262144 B
    short* BT         = (short*)(ws + 262144);             // 131072 B
    int*   flag_count = (int*)(ws + 262144 + 131072);      // @393216
    int*   flag_list  = (int*)(ws + 393216 + 256);         // @393472, 64KB

    prep_kernel<<<NG * NN, 256, 0, stream>>>(codebooks, W_out, Wl, CO, BT, flag_count);
    pq_v16_kernel<<<512, 512, 0, stream>>>(
        features, gumbel, BT, bl, idx_f, flag_count, flag_list);
    fixup_kernel<<<1024, 128, 0, stream>>>(
        features, gumbel, Wl, bl, idx_f, flag_count, flag_list);
    out_kernel<<<T_TOTAL / 16, 256, 0, stream>>>(CO, b_out, idx_f, out);
}